// Round 8
// baseline (1089.786 us; speedup 1.0000x reference)
//
#include <hip/hip_runtime.h>
#include <math.h>

#define G 8192
#define D 1024
#define E 64
#define CAP 160
#define SLAB (E*CAP)                      // 10240 floats per token per tensor
#define OFF_COMB ((size_t)G*SLAB)         // 83886080
#define OFF_LOSS ((size_t)2*(size_t)G*SLAB)
#define OFF_M1 (OFF_LOSS+1)
#define OFF_M2 (OFF_M1+64)

typedef float vf4 __attribute__((ext_vector_type(4)));   // native vector for nt stores

// workspace element offsets (4B elements)
#define W_E1 0
#define W_E2 8192
#define W_G1 32768
#define W_G2 40960
#define W_SP  57408                       // 512 gating blocks * 64 floats -> ends 90176
#define W_FLAG 131072                     // 511 per-gating-block done flags
#define W_READY 131584                    // single READY flag from scanner
#define W_BASE1 132096                    // 32*64 exclusive chunk bases (top-1)
#define W_BASE2 134144                    // 32*64 (top-2)
#define W_C1K  136192                     // 64
#define MAGIC 0x13371337                  // != 0xAAAAAAAA poison, no reset needed

#define NGATE 512
#define NZERO 2048                        // 4 tokens per zero block

// ---------------- Single fused kernel ----------------
// grid 2560 x 256 thr:
//   [0,512):     gating GEMM+softmax+top2 (16 tokens/block). Blocks 0..510 release a
//                done-flag; block 511 additionally becomes the SCANNER: polls flags,
//                builds global chunk histograms + prefix bases + c1k, writes
//                loss/counts, releases READY.
//   [512,2560):  zero blocks — each owns 4 tokens: nt-zero 4x2 slabs (320 KB),
//                acquire-poll READY (single address), compute own tokens' ranks,
//                inject <=2 nonzeros per token per tensor into OWN slab (no race:
//                __syncthreads drains the block's own nt stores first).
// Gating blocks dispatched first -> resident from t=0 -> flags/READY always make
// progress -> no deadlock. READY (~50us) hides under the ~107us write stream.
__global__ __launch_bounds__(256) void k_fused(const float* __restrict__ x,
                                               const float* __restrict__ w,
                                               int* __restrict__ wsi,
                                               float* __restrict__ wsf,
                                               float* __restrict__ out) {
  __shared__ float xs[16][64];            // gating staging (4 KB)
  __shared__ float sp[256];               // gating softmax partials / scanner loss partials
  __shared__ int h1[32][64], h2[32][64];  // scanner histograms (16 KB)
  __shared__ int c1k_s[64], run2_s[64];

  const int t = threadIdx.x;

  if (blockIdx.x >= NGATE) {
    // ================= zero + inject path =================
    const int zb = blockIdx.x - NGATE;    // 0..2047
    const int n0 = zb * 4;                // first of 4 owned tokens (same 256-chunk)
    vf4 z = {0.f, 0.f, 0.f, 0.f};
    vf4* __restrict__ dp = (vf4*)out + (size_t)n0 * (SLAB/4);
    vf4* __restrict__ cp = (vf4*)(out + OFF_COMB) + (size_t)n0 * (SLAB/4);
#pragma unroll
    for (int i = 0; i < 10; ++i) {        // 4 tokens x 10240 floats = 2560 vf4 per tensor
      const int idx = i * 256 + t;
      __builtin_nontemporal_store(z, &dp[idx]);
      __builtin_nontemporal_store(z, &cp[idx]);
    }
    // wait for scanner publication (single flag; transitively orders E1/E2/G/BASE/C1K)
    for (;;) {
      int ok = (__hip_atomic_load(&wsi[W_READY], __ATOMIC_ACQUIRE,
                                  __HIP_MEMORY_SCOPE_AGENT) == MAGIC);
      if (__syncthreads_and(ok)) break;
      __builtin_amdgcn_s_sleep(8);
    }
    // per-wave: rank own token within its chunk, then lane 0 injects
    const int wv = t >> 6, lane = t & 63;
    const int n = n0 + wv;
    const int c = n >> 8, ii = n & 255;
    const int e1 = wsi[W_E1 + n];
    const int e2 = wsi[W_E2 + n];
    int r1 = 0, r2 = 0;
#pragma unroll
    for (int k = 0; k < 4; ++k) {
      const int j = k * 64 + lane;
      const int a  = wsi[W_E1 + c * 256 + j];
      const int b2 = wsi[W_E2 + c * 256 + j];
      if (j < ii) { r1 += (a == e1); r2 += (b2 == e2); }
    }
    for (int off = 32; off > 0; off >>= 1) {
      r1 += __shfl_xor(r1, off, 64);
      r2 += __shfl_xor(r2, off, 64);
    }
    if (lane == 0) {
      const int p1 = wsi[W_BASE1 + c * 64 + e1] + r1;
      const int p2 = wsi[W_BASE2 + c * 64 + e2] + r2 + wsi[W_C1K + e2];
      const float g1 = wsf[W_G1 + n];
      const float g2 = wsf[W_G2 + n];
      const size_t base = (size_t)n * SLAB;
      // combine entry exists iff position < CAP and gate nonzero
      // (dispatch = (combine != 0), so gate underflow-to-0 must kill dispatch too)
      if (p1 < CAP && g1 != 0.0f) {
        out[base + e1 * CAP + p1] = 1.0f;
        out[OFF_COMB + base + e1 * CAP + p1] = g1;
      }
      if (p2 < CAP && g2 != 0.0f) {
        out[base + e2 * CAP + p2] = 1.0f;
        out[OFF_COMB + base + e2 * CAP + p2] = g2;
      }
    }
    return;
  }

  // ================= gating path =================
  const int lane = t & 63;
  const int wid  = t >> 6;
  const int nblk = blockIdx.x * 16;      // 16 tokens per block
  const int n0   = nblk + wid * 4;       // 4 tokens per wave

  float acc[4] = {0.f, 0.f, 0.f, 0.f};

  const int stok = t >> 4;               // 0..15 (staging token)
  const int sk   = (t & 15) * 4;         // 0..60 (staging k offset)
  const float* xsrc = x + (size_t)(nblk + stok) * D + sk;

  for (int kc = 0; kc < D; kc += 64) {
    *(float4*)&xs[stok][sk] = *(const float4*)(xsrc + kc);
    float wr[64];
#pragma unroll
    for (int j = 0; j < 64; ++j) wr[j] = w[(size_t)(kc + j) * E + lane];
    __syncthreads();
#pragma unroll
    for (int tt = 0; tt < 4; ++tt) {
      const int tok = wid * 4 + tt;
      float a = acc[tt];
#pragma unroll
      for (int j4 = 0; j4 < 16; ++j4) {
        const float4 xv = *(const float4*)&xs[tok][j4 * 4];   // broadcast b128
        a = fmaf(xv.x, wr[j4*4+0], a);
        a = fmaf(xv.y, wr[j4*4+1], a);
        a = fmaf(xv.z, wr[j4*4+2], a);
        a = fmaf(xv.w, wr[j4*4+3], a);
      }
      acc[tt] = a;
    }
    __syncthreads();
  }

  float ps = 0.f;
  for (int tt = 0; tt < 4; ++tt) {
    float v = acc[tt];
    // top-1 (stable: lowest index on ties, matches jax.lax.top_k)
    float m = v; int mi = lane;
    for (int off = 32; off > 0; off >>= 1) {
      float ov = __shfl_xor(m, off, 64);
      int   oi = __shfl_xor(mi, off, 64);
      if (ov > m || (ov == m && oi < mi)) { m = ov; mi = oi; }
    }
    // top-2
    float v2 = (lane == mi) ? -__builtin_inff() : v;
    float m2 = v2; int mi2 = lane;
    for (int off = 32; off > 0; off >>= 1) {
      float ov = __shfl_xor(m2, off, 64);
      int   oi = __shfl_xor(mi2, off, 64);
      if (ov > m2 || (ov == m2 && oi < mi2)) { m2 = ov; mi2 = oi; }
    }
    float ex = expf(v - m);
    float den = ex;
    for (int off = 32; off > 0; off >>= 1) den += __shfl_xor(den, off, 64);
    ps += ex / den;

    float g1 = 1.0f / den;            // exp(0)/den
    float g2 = expf(m2 - m) / den;
    float s  = g1 + g2 + 1e-9f;
    float ga = g1 / s, gb = g2 / s;
    if (lane == 0) {
      int n = n0 + tt;
      wsi[W_E1 + n] = mi;
      wsi[W_E2 + n] = mi2;
      wsf[W_G1 + n] = ga;
      wsf[W_G2 + n] = gb;
    }
  }
  sp[t] = ps;
  __syncthreads();
  if (t < 64) {
    wsf[W_SP + blockIdx.x * 64 + t] =
      sp[t] + sp[64 + t] + sp[128 + t] + sp[192 + t];
  }
  __syncthreads();

  if (blockIdx.x != NGATE - 1) {
    if (t == 0) {
      __threadfence();   // publish this block's writes device-wide
      __hip_atomic_store(&wsi[W_FLAG + blockIdx.x], MAGIC,
                         __ATOMIC_RELEASE, __HIP_MEMORY_SCOPE_AGENT);
    }
    return;
  }

  // ================= scanner (gating block 511) =================
  // wait for the other 511 gating blocks
  for (;;) {
    int done = 1;
    for (int i = t; i < NGATE - 1; i += 256)
      if (__hip_atomic_load(&wsi[W_FLAG + i], __ATOMIC_ACQUIRE,
                            __HIP_MEMORY_SCOPE_AGENT) != MAGIC) done = 0;
    if (__syncthreads_and(done)) break;
    __builtin_amdgcn_s_sleep(2);
  }

  for (int i = t; i < 32 * 64; i += 256) { ((int*)h1)[i] = 0; ((int*)h2)[i] = 0; }
  __syncthreads();
  for (int cc = 0; cc < 32; ++cc) {
    const int n = cc * 256 + t;
    atomicAdd(&h1[cc][wsi[W_E1 + n]], 1);
    atomicAdd(&h2[cc][wsi[W_E2 + n]], 1);
  }
  __syncthreads();
  if (t < 64) {
    int r = 0;
    for (int cc = 0; cc < 32; ++cc) { wsi[W_BASE1 + cc * 64 + t] = r; r += h1[cc][t]; }
    const int c1k = min(r, CAP);
    c1k_s[t] = c1k;
    wsi[W_C1K + t] = c1k;
    out[OFF_M1 + t] = (float)c1k;
    // loss term factor: run1 = r
    h1[0][t] = r;                       // stash run1 for loss below
  } else if (t < 128) {
    const int e = t - 64;
    int r = 0;
    for (int cc = 0; cc < 32; ++cc) { wsi[W_BASE2 + cc * 64 + e] = r; r += h2[cc][e]; }
    run2_s[e] = r;
  }
  __syncthreads();
  if (t < 64)
    out[OFF_M2 + t] = (float)min(run2_s[t], max(0, CAP - c1k_s[t]));

  // loss = mean_e( (sumprob_e/8192) * (run1_e/8192) ) * 64^2
  {
    const int e = t & 63, q = t >> 6;
    float s = 0.f;
    for (int i = 0; i < 128; ++i)
      s += wsf[W_SP + (size_t)(q * 128 + i) * 64 + e];
    sp[t] = s;
  }
  __syncthreads();
  if (t < 64) {
    float s = sp[t] + sp[64 + t] + sp[128 + t] + sp[192 + t];
    float term = (s * (1.0f/8192.f)) * ((float)h1[0][t] * (1.0f/8192.f));
    for (int off = 32; off > 0; off >>= 1) term += __shfl_xor(term, off, 64);
    if (t == 0) out[OFF_LOSS] = (term * (1.0f/64.f)) * 4096.0f;
  }
  __syncthreads();
  if (t == 0) {
    __threadfence();
    __hip_atomic_store(&wsi[W_READY], MAGIC,
                       __ATOMIC_RELEASE, __HIP_MEMORY_SCOPE_AGENT);
  }
}

extern "C" void kernel_launch(void* const* d_in, const int* in_sizes, int n_in,
                              void* d_out, int out_size, void* d_ws, size_t ws_size,
                              hipStream_t stream) {
  const float* x = (const float*)d_in[0];
  const float* w = (const float*)d_in[1];
  float* out = (float*)d_out;
  int*   wsi = (int*)d_ws;
  float* wsf = (float*)d_ws;

  k_fused<<<NGATE + NZERO, 256, 0, stream>>>(x, w, wsi, wsf, out);
}